// Round 1
// baseline (1576.215 us; speedup 1.0000x reference)
//
#include <hip/hip_runtime.h>
#include <math.h>

#define B_ 8
#define T1_ 32
#define T2_ 32
#define T3_ 16
#define D_ 512
#define L_ 20
#define DL_ 128
#define M_ (B_*T1_*T2_*T3_)   // 131072

// workspace layout (float offsets)
#define WS_FW   0                      // B*L*DL = 20480
#define WS_KQ   20480                  // B*L*DL = 20480
#define WS_FS   40960                  // B*DL   = 1024
#define WS_SB   41984                  // B*L    = 160
#define WS_FCCH 42144                  // M*DL   = 16777216
// total = 16,819,360 floats = 67.3 MB

// ---------------------------------------------------------------------------
// K1: tiny projections. grid = B*L blocks, 128 threads.
// f_w_hat = f_w@Ww^T+bw ; f_s_hat = f_s@Ws^T+bs ; k = f_w_hat@Wk^T+bk ;
// kq = k@Wq ; sb = bq.k    (so scores = (f_c_hat . kq + sb)/sqrt(DL))
// ---------------------------------------------------------------------------
__global__ __launch_bounds__(128) void k1_small(
    const float* __restrict__ f_w, const float* __restrict__ f_s,
    const float* __restrict__ Ww, const float* __restrict__ bw,
    const float* __restrict__ Ws, const float* __restrict__ bs,
    const float* __restrict__ Wq, const float* __restrict__ bq,
    const float* __restrict__ Wk, const float* __restrict__ bk,
    float* __restrict__ ws) {
  const int bl = blockIdx.x;          // 0..159
  const int b = bl / L_, l = bl % L_;
  const int d = threadIdx.x;          // 0..127
  __shared__ float s_fw[DL_];
  __shared__ float s_k[DL_];

  // f_w_hat[b][l][d]
  {
    const float* x = f_w + (size_t)(b*L_+l)*D_;
    const float* w = Ww + (size_t)d*D_;
    float acc = 0.f;
    for (int i = 0; i < D_; i += 4)
      acc += x[i]*w[i] + x[i+1]*w[i+1] + x[i+2]*w[i+2] + x[i+3]*w[i+3];
    acc += bw[d];
    s_fw[d] = acc;
    ws[WS_FW + (b*L_+l)*DL_ + d] = acc;
  }
  // f_s_hat (only one block per b does it)
  if (l == 0) {
    const float* x = f_s + (size_t)b*D_;
    const float* w = Ws + (size_t)d*D_;
    float acc = 0.f;
    for (int i = 0; i < D_; i += 4)
      acc += x[i]*w[i] + x[i+1]*w[i+1] + x[i+2]*w[i+2] + x[i+3]*w[i+3];
    ws[WS_FS + b*DL_ + d] = acc + bs[d];
  }
  __syncthreads();
  // k[b][l][d]
  {
    const float* w = Wk + (size_t)d*DL_;
    float acc = 0.f;
    for (int i = 0; i < DL_; ++i) acc += s_fw[i]*w[i];
    s_k[d] = acc + bk[d];
  }
  __syncthreads();
  // kq[b][l][d] = sum_c k[c] * Wq[c][d]
  {
    float acc = 0.f;
    for (int c = 0; c < DL_; ++c) acc += s_k[c] * Wq[c*DL_ + d];
    ws[WS_KQ + (b*L_+l)*DL_ + d] = acc;
  }
  // sb[b][l] = bq . k
  if (d == 0) {
    float acc = 0.f;
    for (int c = 0; c < DL_; ++c) acc += bq[c]*s_k[c];
    ws[WS_SB + b*L_ + l] = acc;
  }
}

// ---------------------------------------------------------------------------
// K2: per 32-row tile (= 2 complete (b,x,y) groups of T3=16):
//  phase1: f_c_hat = f_c @ Wc_down^T + bc_down     (SGEMM, LDS-staged)
//  phase2: scores = (f_c_hat.kq + sb)/sqrt(DL); softmax over L
//  phase3: f_cq = f_c_hat * (attn@f_w_hat + f_s_hat)
//  phase4: A_c = softmax(f_cq f_cq^T / sqrt(DL)) over T3
//  phase5: f_cc_hat = A_c @ f_c_hat  -> global ws
// ---------------------------------------------------------------------------
#define SA_STR 68
#define SB_STR 68
#define FCH_STR 132

__global__ __launch_bounds__(256) void k2_fused(
    const float* __restrict__ f_c, const float* __restrict__ Wc_down,
    const float* __restrict__ bc_down, float* __restrict__ ws) {
  __shared__ float smem[15104];          // 60.4 KB
  float* sA   = smem;                    // [32][68]  phase1
  float* sB   = smem + 2176;             // [128][68] phase1
  float* sFch = smem + 10880;            // [32][132] persists
  // phase>=2 aliases of the sA/sB region:
  float* sKq  = smem;                    // [20][132]
  float* sFw  = smem + 2640;             // [20][132]
  float* sFs  = smem + 5280;             // [128]
  float* sAttn= smem + 5408;             // [32][21]
  float* sFcq = smem + 6080;             // [32][132]
  float* sAc  = smem + 10304;            // [32][17]

  const int t = threadIdx.x;
  const int row0 = blockIdx.x * 32;
  const int b = row0 >> 14;              // /16384
  const int row_g = t >> 5;              // 0..7
  const int col_g = t & 31;              // 0..31
  const float inv_sqrt_dl = 0.08838834764831843f;

  float acc[4][4];
  #pragma unroll
  for (int i = 0; i < 4; ++i)
    #pragma unroll
    for (int j = 0; j < 4; ++j) acc[i][j] = 0.f;

  for (int kc = 0; kc < D_; kc += 64) {
    #pragma unroll
    for (int i = 0; i < 2; ++i) {               // A: 32 rows x 64 k
      int f4 = t + i*256;
      int r = f4 >> 4, k4 = (f4 & 15)*4;
      *(float4*)(sA + r*SA_STR + k4) =
        *(const float4*)(f_c + (size_t)(row0 + r)*D_ + kc + k4);
    }
    #pragma unroll
    for (int i = 0; i < 8; ++i) {               // B: 128 cols x 64 k
      int f4 = t + i*256;
      int c = f4 >> 4, k4 = (f4 & 15)*4;
      *(float4*)(sB + c*SB_STR + k4) =
        *(const float4*)(Wc_down + (size_t)c*D_ + kc + k4);
    }
    __syncthreads();
    #pragma unroll
    for (int k4 = 0; k4 < 64; k4 += 4) {
      float4 a[4], bb[4];
      #pragma unroll
      for (int i = 0; i < 4; ++i)
        a[i] = *(const float4*)(sA + (row_g + 8*i)*SA_STR + k4);
      #pragma unroll
      for (int j = 0; j < 4; ++j)
        bb[j] = *(const float4*)(sB + (col_g + 32*j)*SB_STR + k4);
      #pragma unroll
      for (int i = 0; i < 4; ++i)
        #pragma unroll
        for (int j = 0; j < 4; ++j)
          acc[i][j] += a[i].x*bb[j].x + a[i].y*bb[j].y
                     + a[i].z*bb[j].z + a[i].w*bb[j].w;
    }
    __syncthreads();
  }
  // bias + park f_c_hat tile in LDS
  #pragma unroll
  for (int j = 0; j < 4; ++j) {
    int c = col_g + 32*j;
    float bias = bc_down[c];
    #pragma unroll
    for (int i = 0; i < 4; ++i)
      sFch[(row_g + 8*i)*FCH_STR + c] = acc[i][j] + bias;
  }
  // stage per-batch small tensors into the (now free) sA/sB region
  for (int f4 = t; f4 < L_*32; f4 += 256) {
    int l = f4 >> 5, d4 = (f4 & 31)*4;
    *(float4*)(sKq + l*FCH_STR + d4) =
      *(const float4*)(ws + WS_KQ + (b*L_+l)*DL_ + d4);
    *(float4*)(sFw + l*FCH_STR + d4) =
      *(const float4*)(ws + WS_FW + (b*L_+l)*DL_ + d4);
  }
  if (t < 32)
    *(float4*)(sFs + t*4) = *(const float4*)(ws + WS_FS + b*DL_ + t*4);
  __syncthreads();

  // phase2: scores
  for (int p = t; p < 32*L_; p += 256) {
    int r = p / L_, l = p % L_;
    const float* qr = sFch + r*FCH_STR;
    const float* kr = sKq + l*FCH_STR;
    float s = 0.f;
    #pragma unroll
    for (int k = 0; k < DL_; k += 4) {
      float4 a = *(const float4*)(qr + k);
      float4 c = *(const float4*)(kr + k);
      s += a.x*c.x + a.y*c.y + a.z*c.z + a.w*c.w;
    }
    sAttn[r*21 + l] = (s + ws[WS_SB + b*L_ + l]) * inv_sqrt_dl;
  }
  __syncthreads();
  if (t < 32) {                                // softmax over L
    float* srow = sAttn + t*21;
    float m = -1e30f;
    for (int l = 0; l < L_; ++l) m = fmaxf(m, srow[l]);
    float sum = 0.f;
    for (int l = 0; l < L_; ++l) { float e = __expf(srow[l]-m); srow[l] = e; sum += e; }
    float inv = 1.f/sum;
    for (int l = 0; l < L_; ++l) srow[l] *= inv;
  }
  __syncthreads();
  // phase3: f_cq
  for (int p = t; p < 32*32; p += 256) {
    int r = p >> 5, d4 = (p & 31)*4;
    float ax = 0.f, ay = 0.f, az = 0.f, aw = 0.f;
    for (int l = 0; l < L_; ++l) {
      float a = sAttn[r*21 + l];
      float4 w = *(const float4*)(sFw + l*FCH_STR + d4);
      ax += a*w.x; ay += a*w.y; az += a*w.z; aw += a*w.w;
    }
    float4 fs4 = *(const float4*)(sFs + d4);
    float4 fh  = *(const float4*)(sFch + r*FCH_STR + d4);
    float4 o;
    o.x = fh.x*(ax+fs4.x); o.y = fh.y*(ay+fs4.y);
    o.z = fh.z*(az+fs4.z); o.w = fh.w*(aw+fs4.w);
    *(float4*)(sFcq + r*FCH_STR + d4) = o;
  }
  __syncthreads();
  // phase4: A_c
  for (int p = t; p < 512; p += 256) {
    int g = p >> 8, z = (p >> 4) & 15, w = p & 15;
    const float* xr = sFcq + (g*16+z)*FCH_STR;
    const float* yr = sFcq + (g*16+w)*FCH_STR;
    float s = 0.f;
    #pragma unroll
    for (int k = 0; k < DL_; k += 4) {
      float4 a = *(const float4*)(xr + k);
      float4 c = *(const float4*)(yr + k);
      s += a.x*c.x + a.y*c.y + a.z*c.z + a.w*c.w;
    }
    sAc[(g*16+z)*17 + w] = s * inv_sqrt_dl;
  }
  __syncthreads();
  if (t < 32) {                                // softmax over T3
    float* srow = sAc + t*17;
    float m = -1e30f;
    for (int w = 0; w < 16; ++w) m = fmaxf(m, srow[w]);
    float sum = 0.f;
    for (int w = 0; w < 16; ++w) { float e = __expf(srow[w]-m); srow[w] = e; sum += e; }
    float inv = 1.f/sum;
    for (int w = 0; w < 16; ++w) srow[w] *= inv;
  }
  __syncthreads();
  // phase5: f_cc_hat -> global ws
  for (int p = t; p < 32*32; p += 256) {
    int r = p >> 5, d4 = (p & 31)*4;
    int g = r >> 4, z = r & 15;
    float ax = 0.f, ay = 0.f, az = 0.f, aw = 0.f;
    #pragma unroll
    for (int w = 0; w < 16; ++w) {
      float a = sAc[(g*16+z)*17 + w];
      float4 f = *(const float4*)(sFch + (g*16+w)*FCH_STR + d4);
      ax += a*f.x; ay += a*f.y; az += a*f.z; aw += a*f.w;
    }
    float4 o; o.x = ax; o.y = ay; o.z = az; o.w = aw;
    *(float4*)(ws + WS_FCCH + (size_t)(row0 + r)*DL_ + d4) = o;
  }
}

// ---------------------------------------------------------------------------
// K3: f_cc = f_cc_hat @ Wc_up^T + bc_up, + f_c + sigmoid(f_m*f_s)*f_m
// grid = (D/64, M/64), 256 threads, 64x64 tile, K=128
// ---------------------------------------------------------------------------
__global__ __launch_bounds__(256) void k3_up(
    const float* __restrict__ fcch, const float* __restrict__ Wc_up,
    const float* __restrict__ bc_up, const float* __restrict__ f_c,
    const float* __restrict__ f_m, const float* __restrict__ f_s,
    float* __restrict__ out) {
  __shared__ float sA[64*132];   // f_cc_hat tile [64][128]
  __shared__ float sB[64*68];    // Wc_up chunk  [64][64]
  const int t = threadIdx.x;
  const int row0 = blockIdx.y * 64;
  const int c0g = blockIdx.x * 64;
  const int row_g = t >> 4;      // 0..15
  const int col_g = t & 15;      // 0..15

  #pragma unroll
  for (int i = 0; i < 8; ++i) {
    int f4 = t + i*256;
    int r = f4 >> 5, k4 = (f4 & 31)*4;
    *(float4*)(sA + r*132 + k4) =
      *(const float4*)(fcch + (size_t)(row0 + r)*DL_ + k4);
  }
  float acc[4][4];
  #pragma unroll
  for (int i = 0; i < 4; ++i)
    #pragma unroll
    for (int j = 0; j < 4; ++j) acc[i][j] = 0.f;

  for (int kc = 0; kc < DL_; kc += 64) {
    #pragma unroll
    for (int i = 0; i < 4; ++i) {
      int f4 = t + i*256;
      int c = f4 >> 4, k4 = (f4 & 15)*4;
      *(float4*)(sB + c*68 + k4) =
        *(const float4*)(Wc_up + (size_t)(c0g + c)*DL_ + kc + k4);
    }
    __syncthreads();
    #pragma unroll
    for (int k4 = 0; k4 < 64; k4 += 4) {
      float4 a[4], bb[4];
      #pragma unroll
      for (int i = 0; i < 4; ++i)
        a[i] = *(const float4*)(sA + (row_g + 16*i)*132 + kc + k4);
      #pragma unroll
      for (int j = 0; j < 4; ++j)
        bb[j] = *(const float4*)(sB + (col_g + 16*j)*68 + k4);
      #pragma unroll
      for (int i = 0; i < 4; ++i)
        #pragma unroll
        for (int j = 0; j < 4; ++j)
          acc[i][j] += a[i].x*bb[j].x + a[i].y*bb[j].y
                     + a[i].z*bb[j].z + a[i].w*bb[j].w;
    }
    __syncthreads();
  }
  // epilogue: bias + residual f_c + sigmoid gate on f_m
  const int bidx = row0 >> 14;
  #pragma unroll
  for (int i = 0; i < 4; ++i) {
    const int row = row0 + row_g + 16*i;
    const size_t obase = (size_t)row * D_;
    const size_t mbase = (size_t)(row >> 4) * D_;
    #pragma unroll
    for (int j = 0; j < 4; ++j) {
      const int dc = c0g + col_g + 16*j;
      float fm = f_m[mbase + dc];
      float fsv = f_s[(size_t)bidx*D_ + dc];
      float g = 1.f / (1.f + __expf(-fm*fsv));
      out[obase + dc] = acc[i][j] + bc_up[dc] + f_c[obase + dc] + g*fm;
    }
  }
}

extern "C" void kernel_launch(void* const* d_in, const int* in_sizes, int n_in,
                              void* d_out, int out_size, void* d_ws, size_t ws_size,
                              hipStream_t stream) {
  (void)in_sizes; (void)n_in; (void)out_size; (void)ws_size;
  const float* f_c     = (const float*)d_in[0];
  const float* f_w     = (const float*)d_in[1];
  const float* f_s     = (const float*)d_in[2];
  const float* f_m     = (const float*)d_in[3];
  const float* Wc_down = (const float*)d_in[4];
  const float* bc_down = (const float*)d_in[5];
  const float* Ww      = (const float*)d_in[6];
  const float* bw      = (const float*)d_in[7];
  const float* Ws      = (const float*)d_in[8];
  const float* bs      = (const float*)d_in[9];
  const float* Wq      = (const float*)d_in[10];
  const float* bq      = (const float*)d_in[11];
  const float* Wk      = (const float*)d_in[12];
  const float* bk      = (const float*)d_in[13];
  const float* Wc_up   = (const float*)d_in[14];
  const float* bc_up   = (const float*)d_in[15];
  float* out = (float*)d_out;
  float* ws  = (float*)d_ws;

  hipLaunchKernelGGL(k1_small, dim3(B_*L_), dim3(128), 0, stream,
                     f_w, f_s, Ww, bw, Ws, bs, Wq, bq, Wk, bk, ws);
  hipLaunchKernelGGL(k2_fused, dim3(M_/32), dim3(256), 0, stream,
                     f_c, Wc_down, bc_down, ws);
  hipLaunchKernelGGL(k3_up, dim3(D_/64, M_/64), dim3(256), 0, stream,
                     ws + WS_FCCH, Wc_up, bc_up, f_c, f_m, f_s, out);
}

// Round 2
// 319.652 us; speedup vs baseline: 4.9310x; 4.9310x over previous
//
#include <hip/hip_runtime.h>
#include <math.h>

#define B_ 8
#define T1_ 32
#define T2_ 32
#define T3_ 16
#define D_ 512
#define L_ 20
#define DL_ 128
#define M_ (B_*T1_*T2_*T3_)   // 131072

// workspace layout (float offsets)
#define WS_FW   0                      // B*L*DL = 20480
#define WS_KQ   20480                  // B*L*DL = 20480
#define WS_FS   40960                  // B*DL   = 1024
#define WS_SB   41984                  // B*L    = 160
#define WS_WDB  42144                  // Wc_down bf16: 65536 ushort = 32768 floats
#define WS_WUB  74912                  // Wc_up   bf16: 65536 ushort = 32768 floats

typedef __attribute__((ext_vector_type(8))) short short8_t;
typedef __attribute__((ext_vector_type(4))) float f32x4;

__device__ __forceinline__ unsigned short f2b(float f) {
  unsigned int u = __float_as_uint(f);
  return (unsigned short)((u + 0x7fffu + ((u >> 16) & 1u)) >> 16);
}

// ---------------------------------------------------------------------------
// K0: convert Wc_down [128][512] and Wc_up [512][128] fp32 -> bf16 in ws
// grid = 128 blocks x 256 thr, each thread one float4 (4 elems)
// ---------------------------------------------------------------------------
__global__ __launch_bounds__(256) void k0_convert(
    const float* __restrict__ Wd, const float* __restrict__ Wu,
    unsigned short* __restrict__ wdb, unsigned short* __restrict__ wub) {
  int g = blockIdx.x * 256 + threadIdx.x;      // 0..32767
  if (g < 16384) {
    float4 v = ((const float4*)Wd)[g];
    ushort4 h; h.x = f2b(v.x); h.y = f2b(v.y); h.z = f2b(v.z); h.w = f2b(v.w);
    ((ushort4*)wdb)[g] = h;
  } else {
    int q = g - 16384;
    float4 v = ((const float4*)Wu)[q];
    ushort4 h; h.x = f2b(v.x); h.y = f2b(v.y); h.z = f2b(v.z); h.w = f2b(v.w);
    ((ushort4*)wub)[q] = h;
  }
}

// ---------------------------------------------------------------------------
// K1: tiny projections (unchanged). grid = B*L blocks, 128 threads.
// ---------------------------------------------------------------------------
__global__ __launch_bounds__(128) void k1_small(
    const float* __restrict__ f_w, const float* __restrict__ f_s,
    const float* __restrict__ Ww, const float* __restrict__ bw,
    const float* __restrict__ Ws, const float* __restrict__ bs,
    const float* __restrict__ Wq, const float* __restrict__ bq,
    const float* __restrict__ Wk, const float* __restrict__ bk,
    float* __restrict__ ws) {
  const int bl = blockIdx.x;
  const int b = bl / L_, l = bl % L_;
  const int d = threadIdx.x;
  __shared__ float s_fw[DL_];
  __shared__ float s_k[DL_];
  {
    const float* x = f_w + (size_t)(b*L_+l)*D_;
    const float* w = Ww + (size_t)d*D_;
    float acc = 0.f;
    for (int i = 0; i < D_; i += 4)
      acc += x[i]*w[i] + x[i+1]*w[i+1] + x[i+2]*w[i+2] + x[i+3]*w[i+3];
    acc += bw[d];
    s_fw[d] = acc;
    ws[WS_FW + (b*L_+l)*DL_ + d] = acc;
  }
  if (l == 0) {
    const float* x = f_s + (size_t)b*D_;
    const float* w = Ws + (size_t)d*D_;
    float acc = 0.f;
    for (int i = 0; i < D_; i += 4)
      acc += x[i]*w[i] + x[i+1]*w[i+1] + x[i+2]*w[i+2] + x[i+3]*w[i+3];
    ws[WS_FS + b*DL_ + d] = acc + bs[d];
  }
  __syncthreads();
  {
    const float* w = Wk + (size_t)d*DL_;
    float acc = 0.f;
    for (int i = 0; i < DL_; ++i) acc += s_fw[i]*w[i];
    s_k[d] = acc + bk[d];
  }
  __syncthreads();
  {
    float acc = 0.f;
    for (int c = 0; c < DL_; ++c) acc += s_k[c] * Wq[c*DL_ + d];
    ws[WS_KQ + (b*L_+l)*DL_ + d] = acc;
  }
  if (d == 0) {
    float acc = 0.f;
    for (int c = 0; c < DL_; ++c) acc += bq[c]*s_k[c];
    ws[WS_SB + b*L_ + l] = acc;
  }
}

// ---------------------------------------------------------------------------
// K2: fully fused per 32-row tile:
//  downGEMM (MFMA bf16) -> f_c_hat(LDS f32) -> attn/gate/self-attn (f32) ->
//  f_cc_hat(LDS bf16) -> upGEMM (MFMA bf16) + bias + residual + f_m gate -> out
// ---------------------------------------------------------------------------
// LDS float offsets
#define OF_FCH   0        // [32][132] f32, 4224 floats
#define OF_R2    4224     // region2: down{WdB 4096f + FcB 1024f} / mid{kq,fw} / up{WuB 4096f}
#define OF_KQ    4224     // [20][132] f32
#define OF_FW    6864     // [20][132] f32
#define OF_R3    9504     // region3
#define OF_FCQ   9504     // [32][132] f32
#define OF_ATTN  13728    // [32][21] f32
#define OF_AC    14400    // [32][17] f32
#define OF_FS    14944    // [128] f32
#define SMEM_F   15072    // 60288 bytes
// byte offsets for bf16 tiles
#define WDB_LB   16896    // region2 byte base: Wc_down chunk [128 rows][128B]
#define FCB_B    33280    // f_c chunk bf16 [32 rows][128B]
#define WUB_LB   16896    // up: Wc_up chunk [64 rows][256B]
#define FCCHB_B  38016    // f_cc_hat bf16 [32 rows][256B] (region3 byte base)

__global__ __launch_bounds__(256, 2) void k2_fused(
    const float* __restrict__ f_c, const unsigned short* __restrict__ wdb,
    const unsigned short* __restrict__ wub,
    const float* __restrict__ bc_down, const float* __restrict__ bc_up,
    const float* __restrict__ f_m, const float* __restrict__ f_s,
    const float* __restrict__ ws, float* __restrict__ out) {
  __shared__ float smem[SMEM_F];
  char* smb = (char*)smem;
  float* sFch = smem + OF_FCH;
  float* sKq  = smem + OF_KQ;
  float* sFw  = smem + OF_FW;
  float* sFcq = smem + OF_FCQ;
  float* sAttn= smem + OF_ATTN;
  float* sAc  = smem + OF_AC;
  float* sFs  = smem + OF_FS;

  const int t = threadIdx.x;
  const int row0 = blockIdx.x * 32;
  const int b = row0 >> 14;
  const int lane = t & 63, w = t >> 6;
  const int l15 = lane & 15, l4 = lane >> 4;
  const float inv_sqrt_dl = 0.08838834764831843f;
  const f32x4 z4 = {0.f, 0.f, 0.f, 0.f};

  // ---------------- down GEMM: f_c_hat = f_c @ Wc_down^T + bc_down ----------
  const int dr0 = (w & 1) * 16, dc0 = (w >> 1) * 64;
  f32x4 dacc[4];
  #pragma unroll
  for (int cf = 0; cf < 4; ++cf) dacc[cf] = z4;

  for (int kc = 0; kc < D_; kc += 64) {
    { // stage A: f_c [32 rows][64 k] fp32 -> bf16 swizzled
      int r = t >> 3, dc = t & 7;
      const float* src = f_c + (size_t)(row0 + r)*D_ + kc + dc*8;
      float4 v0 = *(const float4*)(src);
      float4 v1 = *(const float4*)(src + 4);
      int4 pk;
      pk.x = (int)f2b(v0.x) | ((int)f2b(v0.y) << 16);
      pk.y = (int)f2b(v0.z) | ((int)f2b(v0.w) << 16);
      pk.z = (int)f2b(v1.x) | ((int)f2b(v1.y) << 16);
      pk.w = (int)f2b(v1.z) | ((int)f2b(v1.w) << 16);
      *(int4*)(smb + FCB_B + r*128 + ((dc*16) ^ ((r & 7) << 4))) = pk;
    }
    #pragma unroll
    for (int i = 0; i < 4; ++i) { // stage B: Wd chunk [128][64k] bf16
      int idx = t + i*256;
      int c = idx >> 3, dc = idx & 7;
      int4 v = *(const int4*)(wdb + (size_t)c*D_ + kc + dc*8);
      *(int4*)(smb + WDB_LB + c*128 + ((dc*16) ^ ((c & 7) << 4))) = v;
    }
    __syncthreads();
    #pragma unroll
    for (int ks = 0; ks < 2; ++ks) {
      int arow = dr0 + l15;
      short8_t af = *(const short8_t*)(smb + FCB_B + arow*128 +
                     ((ks*64 + l4*16) ^ ((arow & 7) << 4)));
      #pragma unroll
      for (int cf = 0; cf < 4; ++cf) {
        int bcol = dc0 + cf*16 + l15;
        short8_t bfr = *(const short8_t*)(smb + WDB_LB + bcol*128 +
                        ((ks*64 + l4*16) ^ ((bcol & 7) << 4)));
        dacc[cf] = __builtin_amdgcn_mfma_f32_16x16x32_bf16(af, bfr, dacc[cf], 0, 0, 0);
      }
    }
    __syncthreads();
  }
  // write f_c_hat to LDS (f32) with bias; D-layout: col=lane&15, row=(lane>>4)*4+reg
  #pragma unroll
  for (int cf = 0; cf < 4; ++cf) {
    int col = dc0 + cf*16 + l15;
    float bias = bc_down[col];
    #pragma unroll
    for (int r = 0; r < 4; ++r)
      sFch[(dr0 + l4*4 + r)*132 + col] = dacc[cf][r] + bias;
  }
  // stage per-batch small tensors (region2 now free)
  for (int f4 = t; f4 < L_*32; f4 += 256) {
    int l = f4 >> 5, d4 = (f4 & 31)*4;
    *(float4*)(sKq + l*132 + d4) = *(const float4*)(ws + WS_KQ + (b*L_+l)*DL_ + d4);
    *(float4*)(sFw + l*132 + d4) = *(const float4*)(ws + WS_FW + (b*L_+l)*DL_ + d4);
  }
  if (t < 32)
    *(float4*)(sFs + t*4) = *(const float4*)(ws + WS_FS + b*DL_ + t*4);
  __syncthreads();

  // ---------------- phase2: scores + softmax over L ------------------------
  for (int p = t; p < 32*L_; p += 256) {
    int r = p / L_, l = p % L_;
    const float* qr = sFch + r*132;
    const float* kr = sKq + l*132;
    float s = 0.f;
    #pragma unroll
    for (int k = 0; k < DL_; k += 4) {
      float4 a = *(const float4*)(qr + k);
      float4 c = *(const float4*)(kr + k);
      s += a.x*c.x + a.y*c.y + a.z*c.z + a.w*c.w;
    }
    sAttn[r*21 + l] = (s + ws[WS_SB + b*L_ + l]) * inv_sqrt_dl;
  }
  __syncthreads();
  if (t < 32) {
    float* srow = sAttn + t*21;
    float m = -1e30f;
    for (int l = 0; l < L_; ++l) m = fmaxf(m, srow[l]);
    float sum = 0.f;
    for (int l = 0; l < L_; ++l) { float e = __expf(srow[l]-m); srow[l] = e; sum += e; }
    float inv = 1.f/sum;
    for (int l = 0; l < L_; ++l) srow[l] *= inv;
  }
  __syncthreads();
  // ---------------- phase3: f_cq -------------------------------------------
  for (int p = t; p < 32*32; p += 256) {
    int r = p >> 5, d4 = (p & 31)*4;
    float ax = 0.f, ay = 0.f, az = 0.f, aw = 0.f;
    for (int l = 0; l < L_; ++l) {
      float a = sAttn[r*21 + l];
      float4 wv = *(const float4*)(sFw + l*132 + d4);
      ax += a*wv.x; ay += a*wv.y; az += a*wv.z; aw += a*wv.w;
    }
    float4 fs4 = *(const float4*)(sFs + d4);
    float4 fh  = *(const float4*)(sFch + r*132 + d4);
    float4 o;
    o.x = fh.x*(ax+fs4.x); o.y = fh.y*(ay+fs4.y);
    o.z = fh.z*(az+fs4.z); o.w = fh.w*(aw+fs4.w);
    *(float4*)(sFcq + r*132 + d4) = o;
  }
  __syncthreads();
  // ---------------- phase4: A_c + softmax over T3 --------------------------
  for (int p = t; p < 512; p += 256) {
    int g = p >> 8, z = (p >> 4) & 15, wq = p & 15;
    const float* xr = sFcq + (g*16+z)*132;
    const float* yr = sFcq + (g*16+wq)*132;
    float s = 0.f;
    #pragma unroll
    for (int k = 0; k < DL_; k += 4) {
      float4 a = *(const float4*)(xr + k);
      float4 c = *(const float4*)(yr + k);
      s += a.x*c.x + a.y*c.y + a.z*c.z + a.w*c.w;
    }
    sAc[(g*16+z)*17 + wq] = s * inv_sqrt_dl;
  }
  __syncthreads();
  if (t < 32) {
    float* srow = sAc + t*17;
    float m = -1e30f;
    for (int wq = 0; wq < 16; ++wq) m = fmaxf(m, srow[wq]);
    float sum = 0.f;
    for (int wq = 0; wq < 16; ++wq) { float e = __expf(srow[wq]-m); srow[wq] = e; sum += e; }
    float inv = 1.f/sum;
    for (int wq = 0; wq < 16; ++wq) srow[wq] *= inv;
  }
  __syncthreads();
  // ---------------- phase5: f_cc_hat -> LDS bf16 (A-layout, swizzled) ------
  for (int p = t; p < 32*32; p += 256) {
    int r = p >> 5, d4 = (p & 31)*4;
    int g = r >> 4, z = r & 15;
    float ax = 0.f, ay = 0.f, az = 0.f, aw = 0.f;
    #pragma unroll
    for (int wq = 0; wq < 16; ++wq) {
      float a = sAc[(g*16+z)*17 + wq];
      float4 f = *(const float4*)(sFch + (g*16+wq)*132 + d4);
      ax += a*f.x; ay += a*f.y; az += a*f.z; aw += a*f.w;
    }
    short4 pk;
    pk.x = (short)f2b(ax); pk.y = (short)f2b(ay);
    pk.z = (short)f2b(az); pk.w = (short)f2b(aw);
    *(short4*)(smb + FCCHB_B + r*256 + ((d4*2) ^ ((r & 7) << 4))) = pk;
  }
  __syncthreads();

  // ---------------- up GEMM + epilogue -------------------------------------
  const int ur0 = (w & 1) * 16, uc0 = (w >> 1) * 32;
  for (int ch = 0; ch < 8; ++ch) {
    #pragma unroll
    for (int i = 0; i < 4; ++i) { // stage Wu chunk [64 cols][128 k] bf16
      int idx = t + i*256;
      int c = idx >> 4, dc = idx & 15;
      int4 v = *(const int4*)(wub + (size_t)(ch*64 + c)*DL_ + dc*8);
      *(int4*)(smb + WUB_LB + c*256 + ((dc*16) ^ ((c & 7) << 4))) = v;
    }
    __syncthreads();
    f32x4 uacc[2]; uacc[0] = z4; uacc[1] = z4;
    int arow = ur0 + l15;
    #pragma unroll
    for (int ks = 0; ks < 4; ++ks) {
      short8_t af = *(const short8_t*)(smb + FCCHB_B + arow*256 +
                     ((ks*64 + l4*16) ^ ((arow & 7) << 4)));
      #pragma unroll
      for (int cf = 0; cf < 2; ++cf) {
        int bcol = uc0 + cf*16 + l15;
        short8_t bfr = *(const short8_t*)(smb + WUB_LB + bcol*256 +
                        ((ks*64 + l4*16) ^ ((bcol & 7) << 4)));
        uacc[cf] = __builtin_amdgcn_mfma_f32_16x16x32_bf16(af, bfr, uacc[cf], 0, 0, 0);
      }
    }
    #pragma unroll
    for (int cf = 0; cf < 2; ++cf) {
      int gcol = ch*64 + uc0 + cf*16 + l15;
      float bias = bc_up[gcol];
      float fsv = f_s[(size_t)b*D_ + gcol];
      #pragma unroll
      for (int r = 0; r < 4; ++r) {
        int grow = row0 + ur0 + l4*4 + r;
        size_t oi = (size_t)grow*D_ + gcol;
        float fm = f_m[((size_t)(grow >> 4))*D_ + gcol];
        float g = 1.f/(1.f + __expf(-fm*fsv));
        out[oi] = uacc[cf][r] + bias + f_c[oi] + g*fm;
      }
    }
    __syncthreads();
  }
}

extern "C" void kernel_launch(void* const* d_in, const int* in_sizes, int n_in,
                              void* d_out, int out_size, void* d_ws, size_t ws_size,
                              hipStream_t stream) {
  (void)in_sizes; (void)n_in; (void)out_size; (void)ws_size;
  const float* f_c     = (const float*)d_in[0];
  const float* f_w     = (const float*)d_in[1];
  const float* f_s     = (const float*)d_in[2];
  const float* f_m     = (const float*)d_in[3];
  const float* Wc_down = (const float*)d_in[4];
  const float* bc_down = (const float*)d_in[5];
  const float* Ww      = (const float*)d_in[6];
  const float* bw      = (const float*)d_in[7];
  const float* Ws      = (const float*)d_in[8];
  const float* bs      = (const float*)d_in[9];
  const float* Wq      = (const float*)d_in[10];
  const float* bq      = (const float*)d_in[11];
  const float* Wk      = (const float*)d_in[12];
  const float* bk      = (const float*)d_in[13];
  const float* Wc_up   = (const float*)d_in[14];
  const float* bc_up   = (const float*)d_in[15];
  float* out = (float*)d_out;
  float* wsf = (float*)d_ws;
  unsigned short* wdb = (unsigned short*)(wsf + WS_WDB);
  unsigned short* wub = (unsigned short*)(wsf + WS_WUB);

  hipLaunchKernelGGL(k0_convert, dim3(128), dim3(256), 0, stream,
                     Wc_down, Wc_up, wdb, wub);
  hipLaunchKernelGGL(k1_small, dim3(B_*L_), dim3(128), 0, stream,
                     f_w, f_s, Ww, bw, Ws, bs, Wq, bq, Wk, bk, wsf);
  hipLaunchKernelGGL(k2_fused, dim3(M_/32), dim3(256), 0, stream,
                     f_c, wdb, wub, bc_down, bc_up, f_m, f_s, wsf, out);
}